// Round 1
// baseline (788.392 us; speedup 1.0000x reference)
//
#include <hip/hip_runtime.h>

// GPR-GNN: out = b_fc + sum_k temp[k] * A_hat^k (MLP(x) @ W_fc)
// Key trick: project features to scalar BEFORE propagation (linear ops commute),
// so each hop moves 1 float/node instead of 64.

#define TPB 256

__global__ void k_init_deg(int* __restrict__ deg, int n) {
    int i = blockIdx.x * blockDim.x + threadIdx.x;
    if (i < n) deg[i] = 1;  // self-loop
}

__global__ void k_count(const int* __restrict__ col, int* __restrict__ deg, int e) {
    int i = blockIdx.x * blockDim.x + threadIdx.x;
    if (i < e) atomicAdd(&deg[col[i]], 1);
}

__global__ void k_dinv(const int* __restrict__ deg, float* __restrict__ dinv, int n) {
    int i = blockIdx.x * blockDim.x + threadIdx.x;
    if (i < n) dinv[i] = rsqrtf((float)deg[i]);
}

// Block-level scan: 256 threads x 4 elems = 1024/block. Exclusive within block.
__global__ void k_scan1(const int* __restrict__ deg, int* __restrict__ rowptr,
                        int* __restrict__ bsums, int n) {
    __shared__ int lds[256];
    int t = threadIdx.x;
    int base = blockIdx.x * 1024 + t * 4;
    int v[4]; int s = 0;
#pragma unroll
    for (int j = 0; j < 4; j++) { int idx = base + j; v[j] = (idx < n) ? deg[idx] : 0; s += v[j]; }
    lds[t] = s; __syncthreads();
    for (int o = 1; o < 256; o <<= 1) {
        int a = (t >= o) ? lds[t - o] : 0;
        __syncthreads();
        lds[t] += a;
        __syncthreads();
    }
    int run = lds[t] - s;  // exclusive prefix of this thread's chunk within block
#pragma unroll
    for (int j = 0; j < 4; j++) { int idx = base + j; if (idx < n) rowptr[idx] = run; run += v[j]; }
    if (t == 255) bsums[blockIdx.x] = lds[255];
}

__global__ void k_scan2(int* __restrict__ bsums, int nb) {
    __shared__ int lds[256];
    int t = threadIdx.x;
    int v = (t < nb) ? bsums[t] : 0;
    lds[t] = v; __syncthreads();
    for (int o = 1; o < 256; o <<= 1) {
        int a = (t >= o) ? lds[t - o] : 0;
        __syncthreads();
        lds[t] += a;
        __syncthreads();
    }
    if (t < nb) bsums[t] = lds[t] - v;  // exclusive
}

// Finalize rowptr (add block offsets), place self-loop entry first in each
// node's CSR segment, init fill cursor.
__global__ void k_scan3_fill_self(int* __restrict__ rowptr, const int* __restrict__ bsums,
                                  const float* __restrict__ dinv, int* __restrict__ fill,
                                  int* __restrict__ csr_row, float* __restrict__ csr_w,
                                  int n, int m) {
    int i = blockIdx.x * blockDim.x + threadIdx.x;
    if (i < n) {
        int p = rowptr[i] + bsums[i >> 10];
        rowptr[i] = p;
        fill[i] = p + 1;
        csr_row[p] = i;
        float di = dinv[i];
        csr_w[p] = di * di;   // self-loop weight
    }
    if (i == 0) rowptr[n] = m;
}

__global__ void k_fill_edges(const int* __restrict__ rowi, const int* __restrict__ coli,
                             const float* __restrict__ dinv, int* __restrict__ fill,
                             int* __restrict__ csr_row, float* __restrict__ csr_w, int e) {
    int i = blockIdx.x * blockDim.x + threadIdx.x;
    if (i < e) {
        int r = rowi[i], c = coli[i];
        int pos = atomicAdd(&fill[c], 1);
        csr_row[pos] = r;
        csr_w[pos] = dinv[r] * dinv[c];
    }
}

// One wave per node: lane f computes h2[f] of the MLP, then wave-reduces
// z = h2 . W_fc. Also initializes out = b_fc + temp[0]*z.
__global__ void k_mlp_z(const float* __restrict__ x, const float* __restrict__ W1,
                        const float* __restrict__ b1, const float* __restrict__ W2,
                        const float* __restrict__ b2, const float* __restrict__ Wfc,
                        const float* __restrict__ bfc, const float* __restrict__ temp,
                        float* __restrict__ z, float* __restrict__ out, int n) {
    int wid = (blockIdx.x * blockDim.x + threadIdx.x) >> 6;
    int lane = threadIdx.x & 63;
    if (wid >= n) return;
    float xv = x[wid];
    float acc = b2[lane];
#pragma unroll
    for (int j = 0; j < 32; j++) {
        float h1 = fmaxf(fmaf(xv, W1[j], b1[j]), 0.f);
        acc = fmaf(h1, W2[j * 64 + lane], acc);
    }
    float h2 = fmaxf(acc, 0.f);
    float c = h2 * Wfc[lane];
#pragma unroll
    for (int o = 32; o >= 1; o >>= 1) c += __shfl_xor(c, o);
    if (lane == 0) {
        z[wid] = c;
        out[wid] = fmaf(temp[0], c, bfc[0]);
    }
}

// One wave per node: lanes stride the incoming-edge list, gather z, reduce.
__global__ void k_hop(const int* __restrict__ rowptr, const int* __restrict__ csr_row,
                      const float* __restrict__ csr_w, const float* __restrict__ zin,
                      float* __restrict__ zout, float* __restrict__ out,
                      const float* __restrict__ temp, int k, int n) {
    int wid = (blockIdx.x * blockDim.x + threadIdx.x) >> 6;
    int lane = threadIdx.x & 63;
    if (wid >= n) return;
    int s = rowptr[wid];
    int epos = rowptr[wid + 1];
    float sum = 0.f;
    for (int i = s + lane; i < epos; i += 64)
        sum = fmaf(csr_w[i], zin[csr_row[i]], sum);
#pragma unroll
    for (int o = 32; o >= 1; o >>= 1) sum += __shfl_xor(sum, o);
    if (lane == 0) {
        zout[wid] = sum;
        out[wid] = fmaf(temp[k], sum, out[wid]);
    }
}

static inline size_t align256(size_t x) { return (x + 255) & ~(size_t)255; }

extern "C" void kernel_launch(void* const* d_in, const int* in_sizes, int n_in,
                              void* d_out, int out_size, void* d_ws, size_t ws_size,
                              hipStream_t stream) {
    const float* x    = (const float*)d_in[0];
    const int*   ei   = (const int*)d_in[1];
    const float* W1   = (const float*)d_in[2];
    const float* b1   = (const float*)d_in[3];
    const float* W2   = (const float*)d_in[4];
    const float* b2   = (const float*)d_in[5];
    const float* temp = (const float*)d_in[6];
    const float* Wfc  = (const float*)d_in[7];
    const float* bfc  = (const float*)d_in[8];

    const int n = in_sizes[0];        // 100000 nodes
    const int e = in_sizes[1] / 2;    // 3.2M edges
    const int K = in_sizes[6] - 1;    // 10 hops
    const int m = e + n;              // edges incl. self-loops

    const int* erow = ei;             // edge_index[0] = source
    const int* ecol = ei + e;         // edge_index[1] = target

    float* out = (float*)d_out;

    // workspace carve
    char* ws = (char*)d_ws;
    int*   deg     = (int*)ws;   ws += align256((size_t)n * 4);
    float* dinv    = (float*)ws; ws += align256((size_t)n * 4);
    int*   rowptr  = (int*)ws;   ws += align256((size_t)(n + 1) * 4);
    int*   fill    = (int*)ws;   ws += align256((size_t)n * 4);
    int*   bsums   = (int*)ws;   ws += align256((size_t)512 * 4);
    int*   csr_row = (int*)ws;   ws += align256((size_t)m * 4);
    float* csr_w   = (float*)ws; ws += align256((size_t)m * 4);
    float* z0      = (float*)ws; ws += align256((size_t)n * 4);
    float* z1      = (float*)ws; ws += align256((size_t)n * 4);

    const int gN  = (n + TPB - 1) / TPB;
    const int gE  = (e + TPB - 1) / TPB;
    const int nb  = (n + 1023) / 1024;           // scan blocks (98 for 100k)
    const int gW  = (n + 3) / 4;                 // wave-per-node grids (4 waves/block)

    // --- CSR build (per launch; ws is re-poisoned each call) ---
    k_init_deg<<<gN, TPB, 0, stream>>>(deg, n);
    k_count<<<gE, TPB, 0, stream>>>(ecol, deg, e);
    k_dinv<<<gN, TPB, 0, stream>>>(deg, dinv, n);
    k_scan1<<<nb, 256, 0, stream>>>(deg, rowptr, bsums, n);
    k_scan2<<<1, 256, 0, stream>>>(bsums, nb);
    k_scan3_fill_self<<<gN, TPB, 0, stream>>>(rowptr, bsums, dinv, fill, csr_row, csr_w, n, m);
    k_fill_edges<<<gE, TPB, 0, stream>>>(erow, ecol, dinv, fill, csr_row, csr_w, e);

    // --- MLP + projection to scalar z; init out with temp[0] term ---
    k_mlp_z<<<gW, 256, 0, stream>>>(x, W1, b1, W2, b2, Wfc, bfc, temp, z0, out, n);

    // --- K propagation hops on scalars ---
    float* zin = z0;
    float* zout = z1;
    for (int k = 1; k <= K; k++) {
        k_hop<<<gW, 256, 0, stream>>>(rowptr, csr_row, csr_w, zin, zout, out, temp, k, n);
        float* t2 = zin; zin = zout; zout = t2;
    }
}